// Round 4
// baseline (768.419 us; speedup 1.0000x reference)
//
#include <hip/hip_runtime.h>
#include <stdint.h>

#define DIMD 512
#define NROWS 65536
#define QOFF 1
#define PERPOFF 33554433
#define PROBSOFF 33554434
#define NELEM 33554432

typedef __attribute__((ext_vector_type(8))) short bf16x8;
typedef __attribute__((ext_vector_type(4))) short s16x4;
typedef __attribute__((ext_vector_type(4))) float f32x4;
typedef __attribute__((ext_vector_type(4))) float f4v;

__device__ __forceinline__ short f2bf(float x){
  uint32_t u = __builtin_bit_cast(uint32_t, x);
  uint32_t r = (u + 0x7fffu + ((u >> 16) & 1u)) >> 16;
  return (short)(uint16_t)r;
}
__device__ __forceinline__ float bf2f(short h){
  return __builtin_bit_cast(float, ((uint32_t)(uint16_t)h) << 16);
}

// nontemporal (evict-first) access for streaming data: keeps weights L2-resident
__device__ __forceinline__ f4v ntld4(const float* p){
  return __builtin_nontemporal_load((const f4v*)p);
}
__device__ __forceinline__ float ntldf(const float* p){
  return __builtin_nontemporal_load(p);
}
__device__ __forceinline__ void ntst(float* p, float v){
  __builtin_nontemporal_store(v, p);
}

// A/P LDS tile layout: [row 64][k 512] bf16, 8-short chunks XOR-swizzled:
//   addr(row, k) = row*512 + (((k>>3) ^ (row&7))<<3) + (k&7)
__device__ __forceinline__ int aoff(int row, int kc){
  return row * 512 + ((kc ^ (row & 7)) << 3);
}

// ---------------- weight conversion ----------------
// Fragged weight layout W'[row 512][k 512]: off = (k>>5)*16384 + row*32 + (k&31).
// Grid 512 = 16 k-slabs x 32 row-groups; each wave writes full 128B lines (coalesced);
// gather reads are L2/L3-resident (inputs are 1 MB each).
__global__ __launch_bounds__(256) void k_convert_w(
    const float* __restrict__ meanW, const float* __restrict__ lvW, const float* __restrict__ emb,
    short* __restrict__ MWfh, short* __restrict__ MWfl,
    short* __restrict__ VWh, short* __restrict__ VWl,
    short* __restrict__ Eb, short* __restrict__ Et, float* __restrict__ enorm)
{
  int s = blockIdx.x >> 5;        // k-slab (0..15)
  int g = blockIdx.x & 31;        // row-group (0..31), 16 rows each
  int t = threadIdx.x;
  int kk = s * 32 + (t & 31);
#pragma unroll
  for (int it = 0; it < 2; ++it){
    int R = g * 16 + (t >> 5) + it * 8;
    long dst = (long)s * 16384 + R * 32 + (t & 31);
    float w = meanW[(long)kk * 512 + R];          // B^T gather
    short h = f2bf(w);
    MWfh[dst] = h; MWfl[dst] = f2bf(w - bf2f(h));
    float v = lvW[(long)kk * 512 + R];
    h = f2bf(v);
    VWh[dst] = h; VWl[dst] = f2bf(v - bf2f(h));
    Et[dst] = f2bf(emb[(long)kk * 512 + R]);      // row = d, k = code
    float e = emb[(long)R * 512 + kk];            // row = code, k = d
    Eb[dst] = f2bf(e);
    float es = e * e;
    es += __shfl_xor(es, 1); es += __shfl_xor(es, 2); es += __shfl_xor(es, 4);
    es += __shfl_xor(es, 8); es += __shfl_xor(es, 16);
    if ((t & 31) == 0) atomicAdd(&enorm[R], es);
  }
}

// ---------------- mega-fused: mean + zlv + S + softmax + quant + loss ----------------
// 1024 blocks x 1024 threads (16 waves, 4/SIMD). Block owns 64 rows x all 512 cols.
// Wave wid: all 64 rows x 32 cols (c0 = wid*32). X lives only in LDS. Streaming data
// (inp/probs/qout) is nontemporal so the 3 MB weight set stays L2-resident.
__global__ __launch_bounds__(1024, 1) void k_fused(
    const float* __restrict__ inp,
    const short* __restrict__ MWfh, const short* __restrict__ MWfl,
    const short* __restrict__ VWh, const short* __restrict__ VWl,
    const short* __restrict__ Eb, const short* __restrict__ Et,
    const float* __restrict__ meanb, const float* __restrict__ lvb,
    const float* __restrict__ enorm,
    float* __restrict__ probs, float* __restrict__ qout,
    float* __restrict__ Pacc, float* __restrict__ lossacc)
{
  __shared__ short Ih[64 * 512];   // 64KB: inp-hi, then X-hi, then P (probs bf16)
  __shared__ short Il[64 * 512];   // 64KB: inp-lo, then X-lo
  __shared__ float rrM[16][64];    // cross-wave reduce (max / loss)
  __shared__ float rrS[16][64];    // cross-wave reduce (xnorm / sum)

  const int tid = threadIdx.x;
  const int n0 = blockIdx.x * 64;
  const int lane = tid & 63, wid = tid >> 6;
  const int q = lane >> 4, m = lane & 15;
  const int c0 = wid * 32;

  // per-wave invariant B offsets (within a k-slab): row = c0 + j*16 + m, chunk q
  int boff0 = (c0 + m) * 32 + q * 8;
  int boff1 = (c0 + 16 + m) * 32 + q * 8;

  // ---- phase 0: inp -> hi/lo bf16 split into LDS (nontemporal reads) ----
  {
    const float* inpb = inp + (long)n0 * 512;
#pragma unroll
    for (int it = 0; it < 8; ++it){
      int fid = tid + it * 1024;          // float4 id; 8192 total = 64 rows x 128
      int row = fid >> 7, f = fid & 127;
      const f4v v = ntld4(inpb + (long)fid * 4);
      short h0 = f2bf(v[0]), h1 = f2bf(v[1]), h2 = f2bf(v[2]), h3 = f2bf(v[3]);
      s16x4 hv; hv[0] = h0; hv[1] = h1; hv[2] = h2; hv[3] = h3;
      s16x4 lv;
      lv[0] = f2bf(v[0] - bf2f(h0)); lv[1] = f2bf(v[1] - bf2f(h1));
      lv[2] = f2bf(v[2] - bf2f(h2)); lv[3] = f2bf(v[3] - bf2f(h3));
      int ch = (f >> 1) ^ (row & 7);
      int addr = row * 512 + (ch << 3) + (f & 1) * 4;
      *(s16x4*)(Ih + addr) = hv;
      *(s16x4*)(Il + addr) = lv;
    }
  }
  __syncthreads();

  // ---- phase 1: mean GEMM  x = inp @ meanW  (3-term split; A from LDS, B prefetched) ----
  f32x4 accM[4][2];
#pragma unroll
  for (int i = 0; i < 4; i++)
#pragma unroll
    for (int j = 0; j < 2; j++)
#pragma unroll
      for (int r = 0; r < 4; r++) accM[i][j][r] = 0.f;
  {
    bf16x8 nbh0 = *(const bf16x8*)(MWfh + boff0);
    bf16x8 nbh1 = *(const bf16x8*)(MWfh + boff1);
    bf16x8 nbl0 = *(const bf16x8*)(MWfl + boff0);
    bf16x8 nbl1 = *(const bf16x8*)(MWfl + boff1);
#pragma unroll 2
    for (int ks = 0; ks < 16; ++ks){
      bf16x8 bh0 = nbh0, bh1 = nbh1, bl0 = nbl0, bl1 = nbl1;
      if (ks < 15){
        int o = (ks + 1) * 16384;
        nbh0 = *(const bf16x8*)(MWfh + o + boff0);
        nbh1 = *(const bf16x8*)(MWfh + o + boff1);
        nbl0 = *(const bf16x8*)(MWfl + o + boff0);
        nbl1 = *(const bf16x8*)(MWfl + o + boff1);
      }
      bf16x8 ah[4], al[4];
#pragma unroll
      for (int i = 0; i < 4; i++){
        int off = aoff(i * 16 + m, ks * 4 + q);
        ah[i] = *(const bf16x8*)(Ih + off);
        al[i] = *(const bf16x8*)(Il + off);
      }
      __builtin_amdgcn_s_setprio(1);
#pragma unroll
      for (int i = 0; i < 4; i++){
        accM[i][0] = __builtin_amdgcn_mfma_f32_16x16x32_bf16(ah[i], bh0, accM[i][0], 0, 0, 0);
        accM[i][0] = __builtin_amdgcn_mfma_f32_16x16x32_bf16(ah[i], bl0, accM[i][0], 0, 0, 0);
        accM[i][0] = __builtin_amdgcn_mfma_f32_16x16x32_bf16(al[i], bh0, accM[i][0], 0, 0, 0);
        accM[i][1] = __builtin_amdgcn_mfma_f32_16x16x32_bf16(ah[i], bh1, accM[i][1], 0, 0, 0);
        accM[i][1] = __builtin_amdgcn_mfma_f32_16x16x32_bf16(ah[i], bl1, accM[i][1], 0, 0, 0);
        accM[i][1] = __builtin_amdgcn_mfma_f32_16x16x32_bf16(al[i], bh1, accM[i][1], 0, 0, 0);
      }
      __builtin_amdgcn_s_setprio(0);
    }
  }
  __syncthreads();   // all waves done reading inp split

  // ---- phase 2: X write-back in place (hi/lo) + xnorm partials ----
  {
    float b0 = meanb[c0 + m], b1 = meanb[c0 + 16 + m];
#pragma unroll
    for (int i = 0; i < 4; i++)
#pragma unroll
      for (int r = 0; r < 4; r++){
        int row = i * 16 + q * 4 + r;
        float x0 = accM[i][0][r] + b0;
        float x1 = accM[i][1][r] + b1;
        int col0 = c0 + m, col1 = c0 + 16 + m;
        short h0 = f2bf(x0), h1 = f2bf(x1);
        int a0 = row * 512 + ((((col0 >> 3) ^ (row & 7)) << 3) | (col0 & 7));
        int a1 = row * 512 + ((((col1 >> 3) ^ (row & 7)) << 3) | (col1 & 7));
        Ih[a0] = h0; Il[a0] = f2bf(x0 - bf2f(h0));
        Ih[a1] = h1; Il[a1] = f2bf(x1 - bf2f(h1));
        float xn = x0 * x0 + x1 * x1;
        xn += __shfl_xor(xn, 1); xn += __shfl_xor(xn, 2);
        xn += __shfl_xor(xn, 4); xn += __shfl_xor(xn, 8);
        if (m == 0) rrS[wid][row] = xn;
      }
  }
  __syncthreads();   // X + xnorm partials visible

  // xnorm: lane l holds full sum of row l, then broadcast
  float xnv[4][4];
  {
    float v = 0.f;
#pragma unroll
    for (int w = 0; w < 16; w++) v += rrS[w][lane];
#pragma unroll
    for (int i = 0; i < 4; i++)
#pragma unroll
      for (int r = 0; r < 4; r++) xnv[i][r] = __shfl(v, i * 16 + q * 4 + r);
  }

  // ---- phase 3: Z GEMM  zlv = x @ logvar_W  (3-term split) ----
  f32x4 accZ[4][2];
#pragma unroll
  for (int i = 0; i < 4; i++)
#pragma unroll
    for (int j = 0; j < 2; j++)
#pragma unroll
      for (int r = 0; r < 4; r++) accZ[i][j][r] = 0.f;
  {
    bf16x8 nbh0 = *(const bf16x8*)(VWh + boff0);
    bf16x8 nbh1 = *(const bf16x8*)(VWh + boff1);
    bf16x8 nbl0 = *(const bf16x8*)(VWl + boff0);
    bf16x8 nbl1 = *(const bf16x8*)(VWl + boff1);
#pragma unroll 2
    for (int ks = 0; ks < 16; ++ks){
      bf16x8 bh0 = nbh0, bh1 = nbh1, bl0 = nbl0, bl1 = nbl1;
      if (ks < 15){
        int o = (ks + 1) * 16384;
        nbh0 = *(const bf16x8*)(VWh + o + boff0);
        nbh1 = *(const bf16x8*)(VWh + o + boff1);
        nbl0 = *(const bf16x8*)(VWl + o + boff0);
        nbl1 = *(const bf16x8*)(VWl + o + boff1);
      }
      bf16x8 ah[4], al[4];
#pragma unroll
      for (int i = 0; i < 4; i++){
        int off = aoff(i * 16 + m, ks * 4 + q);
        ah[i] = *(const bf16x8*)(Ih + off);
        al[i] = *(const bf16x8*)(Il + off);
      }
      __builtin_amdgcn_s_setprio(1);
#pragma unroll
      for (int i = 0; i < 4; i++){
        accZ[i][0] = __builtin_amdgcn_mfma_f32_16x16x32_bf16(ah[i], bh0, accZ[i][0], 0, 0, 0);
        accZ[i][0] = __builtin_amdgcn_mfma_f32_16x16x32_bf16(ah[i], bl0, accZ[i][0], 0, 0, 0);
        accZ[i][0] = __builtin_amdgcn_mfma_f32_16x16x32_bf16(al[i], bh0, accZ[i][0], 0, 0, 0);
        accZ[i][1] = __builtin_amdgcn_mfma_f32_16x16x32_bf16(ah[i], bh1, accZ[i][1], 0, 0, 0);
        accZ[i][1] = __builtin_amdgcn_mfma_f32_16x16x32_bf16(ah[i], bl1, accZ[i][1], 0, 0, 0);
        accZ[i][1] = __builtin_amdgcn_mfma_f32_16x16x32_bf16(al[i], bh1, accZ[i][1], 0, 0, 0);
      }
      __builtin_amdgcn_s_setprio(0);
    }
  }

  // ---- phase 4: S GEMM  S = x_hi @ E^T ----
  f32x4 accS[4][2];
#pragma unroll
  for (int i = 0; i < 4; i++)
#pragma unroll
    for (int j = 0; j < 2; j++)
#pragma unroll
      for (int r = 0; r < 4; r++) accS[i][j][r] = 0.f;
  {
    bf16x8 nb0 = *(const bf16x8*)(Eb + boff0);
    bf16x8 nb1 = *(const bf16x8*)(Eb + boff1);
#pragma unroll 2
    for (int ks = 0; ks < 16; ++ks){
      bf16x8 b0 = nb0, b1 = nb1;
      if (ks < 15){
        int o = (ks + 1) * 16384;
        nb0 = *(const bf16x8*)(Eb + o + boff0);
        nb1 = *(const bf16x8*)(Eb + o + boff1);
      }
      bf16x8 ah[4];
#pragma unroll
      for (int i = 0; i < 4; i++)
        ah[i] = *(const bf16x8*)(Ih + aoff(i * 16 + m, ks * 4 + q));
      __builtin_amdgcn_s_setprio(1);
#pragma unroll
      for (int i = 0; i < 4; i++){
        accS[i][0] = __builtin_amdgcn_mfma_f32_16x16x32_bf16(ah[i], b0, accS[i][0], 0, 0, 0);
        accS[i][1] = __builtin_amdgcn_mfma_f32_16x16x32_bf16(ah[i], b1, accS[i][1], 0, 0, 0);
      }
      __builtin_amdgcn_s_setprio(0);
    }
  }

  // ---- logits (in-register) ----
  {
    float lvb0 = lvb[c0 + m], lvb1 = lvb[c0 + 16 + m];
    float en0 = enorm[c0 + m], en1 = enorm[c0 + 16 + m];
    const float inv800 = 0.5f / 400.0f;
#pragma unroll
    for (int i = 0; i < 4; i++)
#pragma unroll
      for (int r = 0; r < 4; r++){
        float z0 = accZ[i][0][r] + lvb0;
        float z1 = accZ[i][1][r] + lvb1;
        float sm0 = __expf(-2.f * z0), sm1 = __expf(-2.f * z1);
        accS[i][0][r] = z0 - inv800 * (xnv[i][r] + en0 - 2.f * accS[i][0][r]) * sm0;
        accS[i][1][r] = z1 - inv800 * (xnv[i][r] + en1 - 2.f * accS[i][1][r]) * sm1;
      }
  }

  // ---- softmax: row max ----
#pragma unroll
  for (int i = 0; i < 4; i++)
#pragma unroll
    for (int r = 0; r < 4; r++){
      float v = fmaxf(accS[i][0][r], accS[i][1][r]);
      v = fmaxf(v, __shfl_xor(v, 1));
      v = fmaxf(v, __shfl_xor(v, 2));
      v = fmaxf(v, __shfl_xor(v, 4));
      v = fmaxf(v, __shfl_xor(v, 8));
      if (m == 0) rrM[wid][i * 16 + q * 4 + r] = v;
    }
  __syncthreads();
  float mxf[4][4];
  {
    float v = rrM[0][lane];
#pragma unroll
    for (int w = 1; w < 16; w++) v = fmaxf(v, rrM[w][lane]);
#pragma unroll
    for (int i = 0; i < 4; i++)
#pragma unroll
      for (int r = 0; r < 4; r++) mxf[i][r] = __shfl(v, i * 16 + q * 4 + r);
  }

  // ---- softmax: exp + row sum ----
#pragma unroll
  for (int i = 0; i < 4; i++)
#pragma unroll
    for (int r = 0; r < 4; r++){
      float p0 = __expf(accS[i][0][r] - mxf[i][r]);
      float p1 = __expf(accS[i][1][r] - mxf[i][r]);
      accS[i][0][r] = p0; accS[i][1][r] = p1;
      float sacc = p0 + p1;
      sacc += __shfl_xor(sacc, 1);
      sacc += __shfl_xor(sacc, 2);
      sacc += __shfl_xor(sacc, 4);
      sacc += __shfl_xor(sacc, 8);
      if (m == 0) rrS[wid][i * 16 + q * 4 + r] = sacc;
    }
  __syncthreads();
  float smr[4][4];
  {
    float v = 0.f;
#pragma unroll
    for (int w = 0; w < 16; w++) v += rrS[w][lane];
#pragma unroll
    for (int i = 0; i < 4; i++)
#pragma unroll
      for (int r = 0; r < 4; r++) smr[i][r] = __shfl(v, i * 16 + q * 4 + r);
  }

  // ---- probs: fp32 global (nt) + bf16 into P (over Ih) + Pacc ----
  {
    float pj0 = 0.f, pj1 = 0.f;
#pragma unroll
    for (int i = 0; i < 4; i++)
#pragma unroll
      for (int r = 0; r < 4; r++){
        int row = i * 16 + q * 4 + r;
        long rowg = n0 + row;
        float inv = 1.0f / smr[i][r];
        float q0 = accS[i][0][r] * inv;
        float q1 = accS[i][1][r] * inv;
        int col0 = c0 + m, col1 = c0 + 16 + m;
        ntst(&probs[rowg * 512 + col0], q0);
        ntst(&probs[rowg * 512 + col1], q1);
        pj0 += q0; pj1 += q1;
        int a0 = row * 512 + ((((col0 >> 3) ^ (row & 7)) << 3) | (col0 & 7));
        int a1 = row * 512 + ((((col1 >> 3) ^ (row & 7)) << 3) | (col1 & 7));
        Ih[a0] = f2bf(q0);
        Ih[a1] = f2bf(q1);
      }
    pj0 += __shfl_xor(pj0, 16); pj0 += __shfl_xor(pj0, 32);
    pj1 += __shfl_xor(pj1, 16); pj1 += __shfl_xor(pj1, 32);
    if (lane < 16){
      atomicAdd(&Pacc[c0 + m], pj0);
      atomicAdd(&Pacc[c0 + 16 + m], pj1);
    }
  }
  __syncthreads();   // P visible

  // ---- phase 5: quant  q = P @ embedding ----
  f32x4 accQ[4][2];
#pragma unroll
  for (int i = 0; i < 4; i++)
#pragma unroll
    for (int j = 0; j < 2; j++)
#pragma unroll
      for (int r = 0; r < 4; r++) accQ[i][j][r] = 0.f;
  {
    bf16x8 nb0 = *(const bf16x8*)(Et + boff0);
    bf16x8 nb1 = *(const bf16x8*)(Et + boff1);
#pragma unroll 2
    for (int ks = 0; ks < 16; ++ks){
      bf16x8 b0 = nb0, b1 = nb1;
      if (ks < 15){
        int o = (ks + 1) * 16384;
        nb0 = *(const bf16x8*)(Et + o + boff0);
        nb1 = *(const bf16x8*)(Et + o + boff1);
      }
      bf16x8 pa[4];
#pragma unroll
      for (int i = 0; i < 4; i++)
        pa[i] = *(const bf16x8*)(Ih + aoff(i * 16 + m, ks * 4 + q));
      __builtin_amdgcn_s_setprio(1);
#pragma unroll
      for (int i = 0; i < 4; i++){
        accQ[i][0] = __builtin_amdgcn_mfma_f32_16x16x32_bf16(pa[i], b0, accQ[i][0], 0, 0, 0);
        accQ[i][1] = __builtin_amdgcn_mfma_f32_16x16x32_bf16(pa[i], b1, accQ[i][1], 0, 0, 0);
      }
      __builtin_amdgcn_s_setprio(0);
    }
  }

  // ---- quant epilogue: qout (nt) + loss (nt inp reads) ----
  {
    float lsum = 0.f;
#pragma unroll
    for (int i = 0; i < 4; i++)
#pragma unroll
      for (int r = 0; r < 4; r++){
        long rowg = n0 + i * 16 + q * 4 + r;
        float q0 = accQ[i][0][r], q1 = accQ[i][1][r];
        long i0 = rowg * 512 + c0 + m;
        long i1 = rowg * 512 + c0 + 16 + m;
        ntst(&qout[i0], q0);
        ntst(&qout[i1], q1);
        float d0 = q0 - ntldf(&inp[i0]), d1 = q1 - ntldf(&inp[i1]);
        lsum += d0 * d0 + d1 * d1;
      }
    lsum += __shfl_xor(lsum, 32);
    lsum += __shfl_xor(lsum, 16);
    lsum += __shfl_xor(lsum, 8);
    lsum += __shfl_xor(lsum, 4);
    lsum += __shfl_xor(lsum, 2);
    lsum += __shfl_xor(lsum, 1);
    if (lane == 0) rrM[0][wid] = lsum;
  }
  __syncthreads();
  if (tid == 0){
    float t = 0.f;
#pragma unroll
    for (int w = 0; w < 16; w++) t += rrM[0][w];
    atomicAdd(lossacc, t);
  }
}

// ---------------- final: loss + perplexity ----------------
__global__ __launch_bounds__(256) void k_final(
    const float* __restrict__ Pacc, const float* __restrict__ lossacc, float* __restrict__ out)
{
  int tid = threadIdx.x;
  float h = 0.f;
  for (int k = tid; k < 512; k += 256){
    float a = Pacc[k] * (1.0f / 65536.0f);
    h += a * __logf(a + 1e-10f);
  }
  for (int o = 32; o >= 1; o >>= 1) h += __shfl_xor(h, o);
  __shared__ float red[4];
  if ((tid & 63) == 0) red[tid >> 6] = h;
  __syncthreads();
  if (tid == 0){
    float H = red[0] + red[1] + red[2] + red[3];
    out[0] = 1.25f * lossacc[0] * (1.0f / (float)NELEM);
    out[PERPOFF] = __expf(-H);
  }
}

extern "C" void kernel_launch(void* const* d_in, const int* in_sizes, int n_in,
                              void* d_out, int out_size, void* d_ws, size_t ws_size,
                              hipStream_t stream)
{
  const float* inp   = (const float*)d_in[0];
  const float* meanW = (const float*)d_in[1];
  const float* meanb = (const float*)d_in[2];
  const float* lvW   = (const float*)d_in[3];
  const float* lvb   = (const float*)d_in[4];
  const float* emb   = (const float*)d_in[5];
  float* out = (float*)d_out;

  // workspace carve (~3 MB)
  char* w = (char*)d_ws;
  short* MWfh = (short*)w; w += 512 * 512 * 2;   // fragged
  short* MWfl = (short*)w; w += 512 * 512 * 2;
  short* VWh  = (short*)w; w += 512 * 512 * 2;
  short* VWl  = (short*)w; w += 512 * 512 * 2;
  short* Eb   = (short*)w; w += 512 * 512 * 2;
  short* Et   = (short*)w; w += 512 * 512 * 2;
  float* enorm = (float*)w; w += 512 * 4;
  float* stats = (float*)w;                      // Pacc[512] + lossacc
  float* Pacc    = stats;
  float* lossacc = stats + 512;

  // zero enorm (atomic-accumulated now) + Pacc + lossacc (contiguous)
  hipMemsetAsync(enorm, 0, (size_t)(512 + 512 + 16) * 4, stream);

  k_convert_w<<<512, 256, 0, stream>>>(meanW, lvW, emb, MWfh, MWfl, VWh, VWl, Eb, Et, enorm);
  k_fused<<<1024, 1024, 0, stream>>>(inp, MWfh, MWfl, VWh, VWl, Eb, Et, meanb, lvb, enorm,
                                     out + PROBSOFF, out + QOFF, Pacc, lossacc);
  k_final<<<1, 256, 0, stream>>>(Pacc, lossacc, out);
}